// Round 6
// baseline (250.518 us; speedup 1.0000x reference)
//
#include <hip/hip_runtime.h>
#include <hip/hip_fp16.h>

#define NCH   40
#define MORD  16
#define NR    17
#define NY    42
#define NBINS 257
#define FPB   64                 // frames per block == block size (one wave)
#define SLABF (FPB * NBINS)      // 16448 halves
#define YSTR  43                 // per-lane ys row stride (odd -> 2-way banking, free)

// ---------------- compile-time table generation (double precision) ----------------
namespace cfg {

constexpr double PI  = 3.14159265358979323846264338327950288;
constexpr double LN2 = 0.693147180559945309417232121458176568;

constexpr double cexp(double x) {
    double t = 1.0, s = 1.0;
    for (int i = 1; i < 40; ++i) { t *= x / i; s += t; }
    return s;
}

constexpr double clog(double z) {
    double lg = 0.0;
    while (z > 1.4142135623730951) { z *= 0.5; lg += LN2; }
    while (z < 0.7071067811865476) { z *= 2.0; lg -= LN2; }
    double u = (z - 1.0) / (z + 1.0), u2 = u * u, t = u, s = u;
    for (int k = 1; k < 24; ++k) { t *= u2; s += t / (2.0 * k + 1.0); }
    return lg + 2.0 * s;
}

constexpr double ccos(double x) {
    double tp = 2.0 * PI;
    double q = x / tp;
    long long k = (long long)(q + (q >= 0.0 ? 0.5 : -0.5));
    double r = x - (double)k * tp;
    double r2 = r * r, t = 1.0, s = 1.0;
    for (int i = 1; i < 20; ++i) { t *= -r2 / ((2.0 * i - 1.0) * (2.0 * i)); s += t; }
    return s;
}

constexpr double csin(double x) { return ccos(x - PI / 2.0); }

struct Tab {
    int   start[43];     // start[c] = first bin with t_b > c (c = 0..41)
    float w[257];        // per-bin t_b - c for its segment c, in [0,1)
    float eql[NCH];
    float lift[NR];
    float ctf[NR][21];   // folded cosine: r[l] = sum_j ctf[l][j]*(ys[j] + (-1)^l ys[41-j])
    constexpr Tab() : start(), w(), eql(), lift(), ctf() {
        const double lmax  = clog(87.0 / 7.0);
        const double U1127 = lmax / 41.0;
        for (int c = 0; c <= 41; ++c) {
            double thr = 22.4 * (cexp((double)c * U1127) - 1.0);
            int s = (int)thr + 1;
            if (s < 1) s = 1;
            if (s > 256) s = 256;
            start[c] = s;
        }
        start[42] = start[41];
        for (int c = 0; c <= 40; ++c) {
            for (int b = start[c]; b < start[c + 1]; ++b) {
                double mel = 1127.0 * clog(1.0 + (double)b * 31.25 / 700.0);
                double t   = mel / (1127.0 * U1127);
                w[b] = (float)(t - (double)c);
            }
        }
        for (int c = 0; c < NCH; ++c) {
            double cf = 700.0 * (cexp((double)(c + 1) * U1127) - 1.0);
            double f2 = cf * cf;
            double e  = f2 / (f2 + 160000.0);
            e = e * e * (f2 + 1440000.0) / (f2 + 9610000.0);
            eql[c] = (float)e;
        }
        for (int m = 0; m < NR; ++m)
            lift[m] = (float)(1.0 + 11.0 * csin(PI * (double)m / 22.0));
        lift[0] = 2.0f;
        for (int l = 0; l < NR; ++l)
            for (int j = 0; j <= 20; ++j) {
                double s = (j == 0) ? 1.0 : 2.0;
                ctf[l][j] = (float)(s * ccos(PI * (double)(j * l) / 41.0) / 82.0);
            }
    }
};

__device__ constexpr Tab T{};

} // namespace cfg

// ---- one wave per block: coalesced fp32->fp16 LDS staging, thread-per-frame,
// ---- COMPACT code: rolled filterbank/cosine loops (I$-friendly). ----
__global__ __launch_bounds__(FPB) void plp_kernel(const float* __restrict__ x,
                                                  float* __restrict__ out,
                                                  int nframes)
{
    using cfg::T;
    __shared__ __half slab[SLABF];          // 32896 B
    __shared__ float  wlds[NBINS];          // 1028 B (broadcast-hot weight table)
    __shared__ float  ysl[FPB * YSTR];      // 11008 B (per-lane ys, then r)
    const int tid = threadIdx.x;
    const long long F0 = (long long)blockIdx.x * FPB;

    // weight table -> LDS (once per block)
    for (int i = tid; i < NBINS; i += FPB) wlds[i] = T.w[i];

    // ---- staging: coalesced float4 loads, fp16 convert, LDS store ----
    {
        const float4* gsrc = reinterpret_cast<const float4*>(x + F0 * NBINS); // 16B-aligned
        const long long maxq = ((long long)nframes * NBINS) / 4 - (F0 * NBINS) / 4;
        #pragma unroll 16
        for (int k = 0; k < 64; ++k) {
            long long i  = (long long)k * 64 + tid;
            long long ii = (i < maxq) ? i : (maxq - 1);
            float4 g = gsrc[ii];
            __half2 h0 = __halves2half2(__float2half_rn(g.x), __float2half_rn(g.y));
            __half2 h1 = __halves2half2(__float2half_rn(g.z), __float2half_rn(g.w));
            *reinterpret_cast<__half2*>(&slab[i * 4])     = h0;
            *reinterpret_cast<__half2*>(&slab[i * 4 + 2]) = h1;
        }
        if (tid < 16) {                      // tail: float4 indices 4096..4111
            long long i  = 4096 + tid;
            long long ii = (i < maxq) ? i : (maxq - 1);
            float4 g = gsrc[ii];
            __half2 h0 = __halves2half2(__float2half_rn(g.x), __float2half_rn(g.y));
            __half2 h1 = __halves2half2(__float2half_rn(g.z), __float2half_rn(g.w));
            *reinterpret_cast<__half2*>(&slab[i * 4])     = h0;
            *reinterpret_cast<__half2*>(&slab[i * 4 + 2]) = h1;
        }
    }
    __syncthreads();

    const long long frame = F0 + tid;
    if (frame >= nframes) return;
    const __half* fr = slab + tid * NBINS;   // ~2-way banking, free

    // ---- filterbank + compression: ROLLED 41-segment loop, single pass per bin ----
    // fb[s-1] = WA_{s-1} + (SX_s - WA_s), where WA = sum w*x, SX = sum x over segment s
    float prevWA = 0.f;
    #pragma unroll 1
    for (int s = 0; s <= 40; ++s) {
        const int b0 = T.start[s];           // uniform -> scalar loads
        const int b1 = T.start[s + 1];
        float WA = 0.f, SX = 0.f;
        #pragma unroll 4
        for (int b = b0; b < b1; ++b) {
            float xv = __half2float(fr[b]);
            float wv = wlds[b];              // broadcast read, free
            WA = fmaf(wv, xv, WA);
            SX += xv;
        }
        if (s >= 1) {
            float fbv = prevWA + (SX - WA);
            float v   = fmaxf(fbv, 1e-5f) * T.eql[s - 1];
            ysl[tid * YSTR + (s - 1)] = __expf(0.33f * __logf(v));
        }
        prevWA = WA;
    }

    // ---- even/odd fold of y (42 taps incl. duplicated edges) ----
    float ye[21], yo[21];
    {
        float yv[40];
        #pragma unroll
        for (int c = 0; c < 40; ++c) yv[c] = ysl[tid * YSTR + c];
        ye[0] = yv[0] + yv[39];  yo[0] = yv[0] - yv[39];   // ys[0]=yv0, ys[41]=yv39
        #pragma unroll
        for (int j = 1; j <= 20; ++j) {
            float aa = yv[j - 1], bb = yv[40 - j];         // ys[j], ys[41-j]
            ye[j] = aa + bb;  yo[j] = aa - bb;
        }
    }

    // ---- folded cosine transform: ROLLED over l, coefficients from .rodata ----
    #pragma unroll 1
    for (int l = 0; l < NR; ++l) {
        float acc = 0.f;
        if (l & 1) {
            #pragma unroll
            for (int j = 0; j <= 20; ++j) acc = fmaf(T.ctf[l][j], yo[j], acc);
        } else {
            #pragma unroll
            for (int j = 0; j <= 20; ++j) acc = fmaf(T.ctf[l][j], ye[j], acc);
        }
        ysl[tid * YSTR + l] = acc;           // reuse row (ys values dead)
    }

    float r[NR];
    #pragma unroll
    for (int l = 0; l < NR; ++l) r[l] = ysl[tid * YSTR + l];

    // ---- Levinson-Durbin (unrolled, v_rcp) ----
    float a[MORD];
    #pragma unroll
    for (int i = 0; i < MORD; ++i) a[i] = 0.f;
    float E = r[0];
    #pragma unroll
    for (int i = 1; i <= MORD; ++i) {
        float acc = r[i];
        #pragma unroll
        for (int j = 0; j < i - 1; ++j) acc = fmaf(a[j], r[i - 1 - j], acc);
        float k = -acc * __builtin_amdgcn_rcpf(E);
        const int half = (i - 1) / 2;
        #pragma unroll
        for (int j = 0; j < half; ++j) {
            float t1 = a[j], t2 = a[i - 2 - j];
            a[j]         = fmaf(k, t2, t1);
            a[i - 2 - j] = fmaf(k, t1, t2);
        }
        if ((i - 1) & 1) a[half] = fmaf(k, a[half], a[half]);
        a[i - 1] = k;
        E = E * (1.f - k * k);
    }

    // ---- cepstrum: ccs[k]=k*cc[k] so inner fma needs no literal; 1/m hoisted ----
    float cc[NR], ccs[NR];
    #pragma unroll
    for (int m = 1; m <= MORD; ++m) {
        float acc = 0.f;
        #pragma unroll
        for (int k2 = 1; k2 < m; ++k2)
            acc = fmaf(ccs[k2], a[m - k2 - 1], acc);
        float cm = -(a[m - 1] + acc * (1.0f / (float)m));
        cc[m]  = cm;
        ccs[m] = (float)m * cm;              // small-int inline constant
    }

    float o[16];
    #pragma unroll
    for (int m = 1; m <= MORD; ++m) o[m - 1] = cc[m] * T.lift[m];

    float4* op = reinterpret_cast<float4*>(out + (size_t)frame * 16);
    op[0] = make_float4(o[0],  o[1],  o[2],  o[3]);
    op[1] = make_float4(o[4],  o[5],  o[6],  o[7]);
    op[2] = make_float4(o[8],  o[9],  o[10], o[11]);
    op[3] = make_float4(o[12], o[13], o[14], o[15]);
}

extern "C" void kernel_launch(void* const* d_in, const int* in_sizes, int n_in,
                              void* d_out, int out_size, void* d_ws, size_t ws_size,
                              hipStream_t stream) {
    const float* x   = (const float*)d_in[0];
    float*      outp = (float*)d_out;
    int nframes = in_sizes[0] / NBINS;                 // 131072
    int nblocks = (nframes + FPB - 1) / FPB;           // 2048
    plp_kernel<<<nblocks, FPB, 0, stream>>>(x, outp, nframes);
}

// Round 7
// 195.703 us; speedup vs baseline: 1.2801x; 1.2801x over previous
//
#include <hip/hip_runtime.h>
#include <hip/hip_fp16.h>

#define NCH   40
#define MORD  16
#define NR    17
#define NBINS 257
#define FPB   128                // frames per block (2 waves, each computes 64)
#define FSTR  258                // LDS frame stride in halves (129 dwords, odd -> free 2-way)

// ---------------- compile-time table generation (double precision) ----------------
namespace cfg {

constexpr double PI  = 3.14159265358979323846264338327950288;
constexpr double LN2 = 0.693147180559945309417232121458176568;

constexpr double cexp(double x) {
    double t = 1.0, s = 1.0;
    for (int i = 1; i < 40; ++i) { t *= x / i; s += t; }
    return s;
}

constexpr double clog(double z) {
    double lg = 0.0;
    while (z > 1.4142135623730951) { z *= 0.5; lg += LN2; }
    while (z < 0.7071067811865476) { z *= 2.0; lg -= LN2; }
    double u = (z - 1.0) / (z + 1.0), u2 = u * u, t = u, s = u;
    for (int k = 1; k < 24; ++k) { t *= u2; s += t / (2.0 * k + 1.0); }
    return lg + 2.0 * s;
}

constexpr double ccos(double x) {
    double tp = 2.0 * PI;
    double q = x / tp;
    long long k = (long long)(q + (q >= 0.0 ? 0.5 : -0.5));
    double r = x - (double)k * tp;
    double r2 = r * r, t = 1.0, s = 1.0;
    for (int i = 1; i < 20; ++i) { t *= -r2 / ((2.0 * i - 1.0) * (2.0 * i)); s += t; }
    return s;
}

constexpr double csin(double x) { return ccos(x - PI / 2.0); }

struct Tab {
    int   start[43];     // start[c] = first bin with t_b > c
    int   chan[257];     // segment id c(b), 0..40
    float w[257];        // t_b - c(b), in [0,1)
    float eql[NCH];
    float lift[NR];
    float ctf[NR][21];   // folded cosine: r[l] = sum_j ctf[l][j]*(ys[j] +- ys[41-j])
    constexpr Tab() : start(), chan(), w(), eql(), lift(), ctf() {
        const double lmax  = clog(87.0 / 7.0);
        const double U1127 = lmax / 41.0;
        for (int c = 0; c <= 41; ++c) {
            double thr = 22.4 * (cexp((double)c * U1127) - 1.0);
            int s = (int)thr + 1;
            if (s < 1) s = 1;
            if (s > 256) s = 256;
            start[c] = s;
        }
        start[42] = start[41];
        for (int c = 0; c <= 40; ++c) {
            for (int b = start[c]; b < start[c + 1]; ++b) {
                double mel = 1127.0 * clog(1.0 + (double)b * 31.25 / 700.0);
                double t   = mel / (1127.0 * U1127);
                w[b] = (float)(t - (double)c);
                chan[b] = c;
            }
        }
        for (int c = 0; c < NCH; ++c) {
            double cf = 700.0 * (cexp((double)(c + 1) * U1127) - 1.0);
            double f2 = cf * cf;
            double e  = f2 / (f2 + 160000.0);
            e = e * e * (f2 + 1440000.0) / (f2 + 9610000.0);
            eql[c] = (float)e;
        }
        for (int m = 0; m < NR; ++m)
            lift[m] = (float)(1.0 + 11.0 * csin(PI * (double)m / 22.0));
        lift[0] = 2.0f;
        for (int l = 0; l < NR; ++l)
            for (int j = 0; j <= 20; ++j) {
                double s = (j == 0) ? 1.0 : 2.0;
                ctf[l][j] = (float)(s * ccos(PI * (double)(j * l) / 41.0) / 82.0);
            }
    }
};

constexpr Tab T{};

} // namespace cfg

// ---- 128-thread block: coalesced fp32->fp16 staging of 2 slabs, then ALL
// ---- 128 threads (2 in-phase waves) run the register pipeline, 1 frame each.
__global__ __launch_bounds__(FPB) void plp_kernel(const float* __restrict__ x,
                                                  float* __restrict__ out,
                                                  int nframes)
{
    using cfg::T;
    __shared__ __half slab[FPB * FSTR];          // 66048 B -> 2 blocks/CU
    const int tid = threadIdx.x;
    const long long F0 = (long long)blockIdx.x * FPB;

    // ---- staging: 64 rounds, 2 frames per round; bins 1..256 -> LDS idx f*258+(b-1)
    {
        const int s  = tid >> 6;                 // 0/1: which frame of the pair
        const int ll = tid & 63;                 // lane within frame
        __half2* l2 = reinterpret_cast<__half2*>(slab);
        #pragma unroll 8
        for (int r = 0; r < 64; ++r) {
            const int fl = 2 * r + s;            // local frame 0..127
            long long fg = F0 + fl;
            if (fg > (long long)nframes - 1) fg = (long long)nframes - 1;
            const float* g = x + fg * NBINS + 1 + 4 * ll;   // bins 4ll+1..4ll+4
            float x0 = g[0], x1 = g[1], x2 = g[2], x3 = g[3];
            const int d = fl * 129 + 2 * ll;     // half2 index
            l2[d]     = __float22half2_rn(make_float2(x0, x1));
            l2[d + 1] = __float22half2_rn(make_float2(x2, x3));
        }
    }
    __syncthreads();

    const long long frame = F0 + tid;
    if (frame >= nframes) return;
    const __half2* fr2 = reinterpret_cast<const __half2*>(slab) + tid * 129;

    // ---- sparse mel filterbank: literal weights, compile-time channel targets ----
    float fb[NCH];
    #pragma unroll
    for (int c = 0; c < NCH; ++c) fb[c] = 0.f;

    #pragma unroll
    for (int p = 0; p < 128; ++p) {
        float2 xp = __half22float2(fr2[p]);      // bins 2p+1 (x), 2p+2 (y)
        {
            constexpr int b = 1;                 // placeholder to keep scope tidy
            (void)b;
        }
        {
            const int   bb = 2 * p + 1;
            const int   c  = T.chan[bb];
            const float wa = T.w[bb];
            if (c < 40) fb[c]     = fmaf(wa, xp.x, fb[c]);
            if (c >= 1) fb[c - 1] = fmaf(1.0f - wa, xp.x, fb[c - 1]);
        }
        if (2 * p + 2 <= 255) {
            const int   bb = 2 * p + 2;
            const int   c  = T.chan[bb];
            const float wa = T.w[bb];
            if (c < 40) fb[c]     = fmaf(wa, xp.y, fb[c]);
            if (c >= 1) fb[c - 1] = fmaf(1.0f - wa, xp.y, fb[c - 1]);
        }
    }

    // ---- equal-loudness + cube-root compression (fast log/exp), ys in regs ----
    float yv[NCH];
    #pragma unroll
    for (int c = 0; c < NCH; ++c) {
        float v = fmaxf(fb[c], 1e-5f) * T.eql[c];
        yv[c] = __expf(0.33f * __logf(v));
    }

    // ---- even/odd fold of y (42 taps incl. duplicated edges) ----
    float ye[21], yo[21];
    ye[0] = yv[0] + yv[39];  yo[0] = yv[0] - yv[39];       // ys[0], ys[41]
    #pragma unroll
    for (int j = 1; j <= 20; ++j) {
        float aa = yv[j - 1], bb = yv[40 - j];             // ys[j], ys[41-j]
        ye[j] = aa + bb;  yo[j] = aa - bb;
    }

    // ---- folded cosine transform: 17 lags x 21 taps, literal coefficients ----
    float r[NR];
    #pragma unroll
    for (int l = 0; l < NR; ++l) {
        const float* yy = (l & 1) ? yo : ye;
        float acc = 0.f;
        #pragma unroll
        for (int j = 0; j <= 20; ++j) acc = fmaf(T.ctf[l][j], yy[j], acc);
        r[l] = acc;
    }

    // ---- Levinson-Durbin (unrolled, v_rcp) ----
    float a[MORD];
    #pragma unroll
    for (int i = 0; i < MORD; ++i) a[i] = 0.f;
    float E = r[0];
    #pragma unroll
    for (int i = 1; i <= MORD; ++i) {
        float acc = r[i];
        #pragma unroll
        for (int j = 0; j < i - 1; ++j) acc = fmaf(a[j], r[i - 1 - j], acc);
        float k = -acc * __builtin_amdgcn_rcpf(E);
        const int half = (i - 1) / 2;
        #pragma unroll
        for (int j = 0; j < half; ++j) {
            float t1 = a[j], t2 = a[i - 2 - j];
            a[j]         = fmaf(k, t2, t1);
            a[i - 2 - j] = fmaf(k, t1, t2);
        }
        if ((i - 1) & 1) a[half] = fmaf(k, a[half], a[half]);
        a[i - 1] = k;
        E = E * (1.f - k * k);
    }

    // ---- cepstrum (c[0] unused; ccs[k]=k*cc[k] keeps inner fma literal-free) ----
    float cc[NR], ccs[NR];
    #pragma unroll
    for (int m = 1; m <= MORD; ++m) {
        float acc = 0.f;
        #pragma unroll
        for (int k2 = 1; k2 < m; ++k2)
            acc = fmaf(ccs[k2], a[m - k2 - 1], acc);
        float cm = -(a[m - 1] + acc * (1.0f / (float)m));
        cc[m]  = cm;
        ccs[m] = (float)m * cm;
    }

    float o[16];
    #pragma unroll
    for (int m = 1; m <= MORD; ++m) o[m - 1] = cc[m] * T.lift[m];

    float4* op = reinterpret_cast<float4*>(out + (size_t)frame * 16);
    op[0] = make_float4(o[0],  o[1],  o[2],  o[3]);
    op[1] = make_float4(o[4],  o[5],  o[6],  o[7]);
    op[2] = make_float4(o[8],  o[9],  o[10], o[11]);
    op[3] = make_float4(o[12], o[13], o[14], o[15]);
}

extern "C" void kernel_launch(void* const* d_in, const int* in_sizes, int n_in,
                              void* d_out, int out_size, void* d_ws, size_t ws_size,
                              hipStream_t stream) {
    const float* x   = (const float*)d_in[0];
    float*      outp = (float*)d_out;
    int nframes = in_sizes[0] / NBINS;                 // 131072
    int nblocks = (nframes + FPB - 1) / FPB;           // 1024
    plp_kernel<<<nblocks, FPB, 0, stream>>>(x, outp, nframes);
}